// Round 3
// baseline (1369.824 us; speedup 1.0000x reference)
//
#include <hip/hip_runtime.h>
#include <hip/hip_bf16.h>

// GroupedMLP: E=8, T=1024, H=2048, I=5632
// Round 3: 256x256x64 8-wave double-buffered GEMMs with counted vmcnt(8)
// pipeline (T3+T4), setprio around MFMA clusters (T5), and st-style XOR
// swizzle baked into the ws layouts (T2, both-sides via pre-swizzled global).
// XCD-aware block swizzle (T1): one expert per XCD.

#define EXPERTS 8
#define TOK     1024
#define HID     2048
#define INTER   5632
#define I2      (2 * INTER)

typedef __bf16 bf16x8 __attribute__((ext_vector_type(8)));
typedef float  f32x4  __attribute__((ext_vector_type(4)));

__device__ __forceinline__ unsigned short f2bf(float f) {
    union { float f; unsigned u; } v; v.f = f;
    unsigned r = v.u + 0x7FFFu + ((v.u >> 16) & 1u);   // RNE
    return (unsigned short)(r >> 16);
}

__device__ __forceinline__ void gload_lds16(const void* g, void* l) {
    __builtin_amdgcn_global_load_lds(
        (const __attribute__((address_space(1))) void*)g,
        (__attribute__((address_space(3))) void*)l, 16, 0, 0);
}

// swizzled fragment read: tile is [256][64] bf16, element k-slot XORed by row&7
__device__ __forceinline__ bf16x8 ldfrag(const unsigned short* S, int R, int kb) {
    int off = R * 64 + (kb ^ ((R & 7) << 3));
    return *reinterpret_cast<const bf16x8*>(S + off);
}

// ---------------- converts (write swizzled ws layouts) ----------------

// X fp32 -> Xb bf16 [8192][2048], k-slot swizzled by row&7
__global__ __launch_bounds__(256) void k_cvt_x(const float* __restrict__ X,
                                               unsigned short* __restrict__ Xb) {
    size_t base = ((size_t)blockIdx.x * 256 + threadIdx.x) * 8;
    int row = (int)(base >> 11);           // /HID
    int k   = (int)(base & (HID - 1));
    int kp  = k ^ ((row & 7) << 3);
    float4 v0 = *reinterpret_cast<const float4*>(X + base);
    float4 v1 = *reinterpret_cast<const float4*>(X + base + 4);
    uint4 o;
    o.x = (unsigned)f2bf(v0.x) | ((unsigned)f2bf(v0.y) << 16);
    o.y = (unsigned)f2bf(v0.z) | ((unsigned)f2bf(v0.w) << 16);
    o.z = (unsigned)f2bf(v1.x) | ((unsigned)f2bf(v1.y) << 16);
    o.w = (unsigned)f2bf(v1.z) | ((unsigned)f2bf(v1.w) << 16);
    *reinterpret_cast<uint4*>(Xb + (size_t)row * HID + kp) = o;
}

// w1[e][h][2I] fp32 -> w1t[e][pc][h] bf16, pc = 2n + c (GLU interleave), h-slot swizzled
__global__ __launch_bounds__(256) void k_cvt_w1(const float* __restrict__ W1,
                                                unsigned short* __restrict__ W1T) {
    __shared__ unsigned short lds[64][72];
    const int bid = blockIdx.x;
    const int hb = bid % (HID / 64);
    const int pb = (bid / (HID / 64)) % (I2 / 64);
    const int e  = bid / ((HID / 64) * (I2 / 64));
    const int h0 = hb * 64, p0 = pb * 64, n0 = p0 >> 1;
    const float* w1e = W1 + (size_t)e * HID * I2;
    const int t = threadIdx.x;
#pragma unroll
    for (int it = 0; it < 16; ++it) {
        int lin   = it * 256 + t;
        int n_off = lin & 31;
        int c     = (lin >> 5) & 1;
        int h_off = lin >> 6;
        float v = w1e[(size_t)(h0 + h_off) * I2 + c * INTER + n0 + n_off];
        lds[2 * n_off + c][h_off] = f2bf(v);
    }
    __syncthreads();
    unsigned short* o = W1T + (size_t)e * I2 * HID;
#pragma unroll
    for (int it = 0; it < 4; ++it) {
        int lin = it * 256 + t;
        int r   = lin >> 4;
        int co  = (lin & 15) * 4;
        int cop = co ^ ((r & 7) << 3);       // swizzle h-slot by row(pc)&7
        ushort4 v = *reinterpret_cast<ushort4*>(&lds[r][co]);
        *reinterpret_cast<ushort4*>(o + (size_t)(p0 + r) * HID + h0 + cop) = v;
    }
}

// w2[e][i][H] fp32 -> w2t[e][h][i] bf16, i-slot swizzled by h&7
__global__ __launch_bounds__(256) void k_cvt_w2(const float* __restrict__ W2,
                                                unsigned short* __restrict__ W2T) {
    __shared__ unsigned short lds[64][72];
    const int bid = blockIdx.x;
    const int ib = bid % (INTER / 64);
    const int hb = (bid / (INTER / 64)) % (HID / 64);
    const int e  = bid / ((INTER / 64) * (HID / 64));
    const int i0 = ib * 64, h0 = hb * 64;
    const float* w2e = W2 + (size_t)e * INTER * HID;
    const int t = threadIdx.x;
#pragma unroll
    for (int it = 0; it < 16; ++it) {
        int lin   = it * 256 + t;
        int h_off = lin & 63;
        int i_off = lin >> 6;
        float v = w2e[(size_t)(i0 + i_off) * HID + h0 + h_off];
        lds[h_off][i_off] = f2bf(v);
    }
    __syncthreads();
    unsigned short* o = W2T + (size_t)e * HID * INTER;
#pragma unroll
    for (int it = 0; it < 4; ++it) {
        int lin = it * 256 + t;
        int r   = lin >> 4;
        int co  = (lin & 15) * 4;
        int cop = co ^ ((r & 7) << 3);
        ushort4 v = *reinterpret_cast<ushort4*>(&lds[r][co]);
        *reinterpret_cast<ushort4*>(o + (size_t)(h0 + r) * INTER + i0 + cop) = v;
    }
}

// ---------------- 256^2 8-wave GEMM core ----------------
// A [Mrows][ktot], B [Nrows][ktot], both bf16 K-contiguous, pre-swizzled.
// 512 threads = 8 waves (2 row-groups x 4 col-groups), per-wave C = 128x64.
// LDS: 2 buffers x (A 256x64 + B 256x64) = 128 KB (dynamic).

__device__ __forceinline__ void stage_tile(const unsigned short* Ab, const unsigned short* Bb,
                                           int ktot, int k0,
                                           unsigned short* Adst, unsigned short* Bdst,
                                           int t, int w) {
#pragma unroll
    for (int j = 0; j < 4; ++j) {
        int row = j * 64 + (t >> 3);
        int col = (t & 7) * 8;
        gload_lds16(Ab + (size_t)row * ktot + k0 + col, Adst + j * 4096 + w * 512);
        gload_lds16(Bb + (size_t)row * ktot + k0 + col, Bdst + j * 4096 + w * 512);
    }
}

#define MFMA_BF16(a, b, c) __builtin_amdgcn_mfma_f32_16x16x32_bf16(a, b, c, 0, 0, 0)

__device__ __forceinline__ void gemm_core(const unsigned short* Ab, const unsigned short* Bb,
                                          int ktot, int nkt, f32x4 (&acc)[8][4],
                                          unsigned short* lds,
                                          int t, int lane, int w, int wr, int wc) {
    unsigned short* As[2] = { lds,          lds + 32768 };
    unsigned short* Bs[2] = { lds + 16384,  lds + 49152 };

    // prologue: K0 -> buf0, K1 -> buf1; wait K0 (8 of 16 loads), keep K1 in flight
    stage_tile(Ab, Bb, ktot, 0,  As[0], Bs[0], t, w);
    stage_tile(Ab, Bb, ktot, 64, As[1], Bs[1], t, w);
    asm volatile("s_waitcnt vmcnt(8)" ::: "memory");
    __builtin_amdgcn_s_barrier();
    asm volatile("" ::: "memory");

    const int cl = lane & 15;
    const int kb0 = (lane >> 4) << 3;

    for (int kt = 0; kt < nkt; ++kt) {
        const unsigned short* Ac = As[kt & 1];
        const unsigned short* Bc = Bs[kt & 1];
        bf16x8 a[4][2], b[4][2];

        // ---- P1: read A-quad 0 (8) + B pair 0 (4); MFMA q(0,0) ----
#pragma unroll
        for (int i = 0; i < 4; ++i)
#pragma unroll
            for (int k = 0; k < 2; ++k)
                a[i][k] = ldfrag(Ac, wr + i * 16 + cl, k * 32 + kb0);
#pragma unroll
        for (int i = 0; i < 2; ++i)
#pragma unroll
            for (int k = 0; k < 2; ++k)
                b[i][k] = ldfrag(Bc, wc + i * 16 + cl, k * 32 + kb0);
        __builtin_amdgcn_s_barrier();
        __builtin_amdgcn_s_setprio(1);
#pragma unroll
        for (int i = 0; i < 4; ++i)
#pragma unroll
            for (int j = 0; j < 2; ++j)
#pragma unroll
                for (int k = 0; k < 2; ++k)
                    acc[i][j] = MFMA_BF16(a[i][k], b[j][k], acc[i][j]);
        __builtin_amdgcn_s_setprio(0);
        __builtin_amdgcn_s_barrier();

        // ---- P2: read B pair 1 (4); MFMA q(0,1) ----
#pragma unroll
        for (int i = 2; i < 4; ++i)
#pragma unroll
            for (int k = 0; k < 2; ++k)
                b[i][k] = ldfrag(Bc, wc + i * 16 + cl, k * 32 + kb0);
        __builtin_amdgcn_s_barrier();
        __builtin_amdgcn_s_setprio(1);
#pragma unroll
        for (int i = 0; i < 4; ++i)
#pragma unroll
            for (int j = 2; j < 4; ++j)
#pragma unroll
                for (int k = 0; k < 2; ++k)
                    acc[i][j] = MFMA_BF16(a[i][k], b[j][k], acc[i][j]);
        __builtin_amdgcn_s_setprio(0);
        __builtin_amdgcn_s_barrier();

        // ---- P3: read A-quad 1 (8); MFMA q(1,0) ----
#pragma unroll
        for (int i = 0; i < 4; ++i)
#pragma unroll
            for (int k = 0; k < 2; ++k)
                a[i][k] = ldfrag(Ac, wr + 64 + i * 16 + cl, k * 32 + kb0);
        __builtin_amdgcn_s_barrier();
        __builtin_amdgcn_s_setprio(1);
#pragma unroll
        for (int i = 0; i < 4; ++i)
#pragma unroll
            for (int j = 0; j < 2; ++j)
#pragma unroll
                for (int k = 0; k < 2; ++k)
                    acc[4 + i][j] = MFMA_BF16(a[i][k], b[j][k], acc[4 + i][j]);
        __builtin_amdgcn_s_setprio(0);
        __builtin_amdgcn_s_barrier();

        // ---- P4: MFMA q(1,1); end-of-read barrier ----
        __builtin_amdgcn_s_setprio(1);
#pragma unroll
        for (int i = 0; i < 4; ++i)
#pragma unroll
            for (int j = 2; j < 4; ++j)
#pragma unroll
                for (int k = 0; k < 2; ++k)
                    acc[4 + i][j] = MFMA_BF16(a[i][k], b[j][k], acc[4 + i][j]);
        __builtin_amdgcn_s_setprio(0);
        __builtin_amdgcn_s_barrier();           // all waves done reading buf kt&1
        asm volatile("" ::: "memory");

        // ---- stage K(t+2) into the buffer just freed; counted wait ----
        if (kt + 2 < nkt) {
            stage_tile(Ab, Bb, ktot, (kt + 2) * 64, As[kt & 1], Bs[kt & 1], t, w);
            asm volatile("s_waitcnt vmcnt(8)" ::: "memory");   // K(t+1) done, K(t+2) in flight
            __builtin_amdgcn_s_barrier();
            asm volatile("" ::: "memory");
        } else if (kt + 1 < nkt) {
            asm volatile("s_waitcnt vmcnt(0)" ::: "memory");   // last prefetched tile
            __builtin_amdgcn_s_barrier();
            asm volatile("" ::: "memory");
        }
    }
}

// fc1: Xb @ w1t^T -> inter bf16 (GLU fused, swizzled store)
__global__ __launch_bounds__(512, 2) void k_fc1_8p(const unsigned short* __restrict__ Xb,
                                                   const unsigned short* __restrict__ W1T,
                                                   unsigned short* __restrict__ inter) {
    extern __shared__ unsigned short lds[];
    const int hw = blockIdx.x;                 // 1408 blocks = 8 * 176
    const int L  = (hw & 7) * 176 + (hw >> 3); // XCD-contiguous: one expert per XCD
    const int nt = L % 44;
    const int mt = (L / 44) & 3;
    const int e  = L / 176;
    const int t = threadIdx.x, lane = t & 63, w = t >> 6;
    const int wr = (w >> 2) * 128, wc = (w & 3) * 64;
    const int m0 = e * TOK + mt * 256;
    const int n0 = nt * 256;                   // pc-space
    const unsigned short* Ab = Xb  + (size_t)m0 * HID;
    const unsigned short* Bb = W1T + (size_t)e * I2 * HID + (size_t)n0 * HID;

    f32x4 acc[8][4];
#pragma unroll
    for (int i = 0; i < 8; ++i)
#pragma unroll
        for (int j = 0; j < 4; ++j) acc[i][j] = f32x4{0.f, 0.f, 0.f, 0.f};

    gemm_core(Ab, Bb, HID, HID / 64, acc, lds, t, lane, w, wr, wc);

    // epilogue: adjacent pc lanes hold (a,b); even lanes store silu(a)*b
    const int cl = lane & 15;
    const int r0 = (lane >> 4) << 2;
#pragma unroll
    for (int mf = 0; mf < 8; ++mf)
#pragma unroll
        for (int nf = 0; nf < 4; ++nf)
#pragma unroll
            for (int r = 0; r < 4; ++r) {
                float v  = acc[mf][nf][r];
                float pv = __shfl_xor(v, 1);
                if ((lane & 1) == 0) {
                    float s = v / (1.f + __expf(-v)) * pv;
                    int row = m0 + wr + mf * 16 + r0 + r;
                    int pc  = n0 + wc + nf * 16 + cl;
                    int c   = pc >> 1;
                    int c2  = (c & ~63) | ((c & 63) ^ ((row & 7) << 3));  // swizzle
                    inter[(size_t)row * INTER + c2] = f2bf(s);
                }
            }
}

// fc2: inter @ w2t^T -> out fp32
__global__ __launch_bounds__(512, 2) void k_fc2_8p(const unsigned short* __restrict__ A,
                                                   const unsigned short* __restrict__ W2T,
                                                   float* __restrict__ out) {
    extern __shared__ unsigned short lds[];
    const int hw = blockIdx.x;                 // 256 blocks = 8 * 32
    const int L  = (hw & 7) * 32 + (hw >> 3);
    const int nt = L & 7;
    const int mt = (L >> 3) & 3;
    const int e  = L >> 5;
    const int t = threadIdx.x, lane = t & 63, w = t >> 6;
    const int wr = (w >> 2) * 128, wc = (w & 3) * 64;
    const int m0 = e * TOK + mt * 256;
    const int n0 = nt * 256;
    const unsigned short* Ab = A   + (size_t)m0 * INTER;
    const unsigned short* Bb = W2T + (size_t)e * HID * INTER + (size_t)n0 * INTER;

    f32x4 acc[8][4];
#pragma unroll
    for (int i = 0; i < 8; ++i)
#pragma unroll
        for (int j = 0; j < 4; ++j) acc[i][j] = f32x4{0.f, 0.f, 0.f, 0.f};

    gemm_core(Ab, Bb, INTER, INTER / 64, acc, lds, t, lane, w, wr, wc);

    const int cl = lane & 15;
    const int r0 = (lane >> 4) << 2;
#pragma unroll
    for (int mf = 0; mf < 8; ++mf)
#pragma unroll
        for (int nf = 0; nf < 4; ++nf)
#pragma unroll
            for (int r = 0; r < 4; ++r) {
                int row = m0 + wr + mf * 16 + r0 + r;
                int col = n0 + wc + nf * 16 + cl;
                out[(size_t)row * HID + col] = acc[mf][nf][r];
            }
}

// ---------------- fallback (round-1 kernels, need only 92 MB ws) ----------------

#define BM  128
#define BK  64
#define LDK 72

__global__ __launch_bounds__(256) void k_fc1_glu_fb(
    const float* __restrict__ X, const float* __restrict__ W1,
    unsigned short* __restrict__ inter)
{
    __shared__ unsigned short As[BM][LDK];
    __shared__ unsigned short Bs[128][LDK];
    const int bid = blockIdx.x;
    const int nt  = bid % (INTER / 64);
    const int mt  = (bid / (INTER / 64)) % (TOK / BM);
    const int e   = bid / ((INTER / 64) * (TOK / BM));
    const int t = threadIdx.x, lane = t & 63, w = t >> 6;
    const int m0 = mt * BM;
    const int rowbase = e * TOK + m0;
    f32x4 acc[2][8];
#pragma unroll
    for (int i = 0; i < 2; ++i)
#pragma unroll
        for (int jj = 0; jj < 8; ++jj) acc[i][jj] = f32x4{0.f, 0.f, 0.f, 0.f};
    const int jcol = t & 127;
    const int hf   = t >> 7;
    const int gcol = (jcol < 64) ? (nt * 64 + jcol) : (INTER + nt * 64 + (jcol - 64));
    const float* w1e = W1 + (size_t)e * HID * I2;
    for (int k0 = 0; k0 < HID; k0 += BK) {
#pragma unroll
        for (int it = 0; it < 8; ++it) {
            int lin = it * 256 + t;
            int r   = lin >> 4;
            int kq  = (lin & 15) << 2;
            const float4 v = *reinterpret_cast<const float4*>(
                X + (size_t)(rowbase + r) * HID + k0 + kq);
            ushort4 o;
            o.x = f2bf(v.x); o.y = f2bf(v.y); o.z = f2bf(v.z); o.w = f2bf(v.w);
            *reinterpret_cast<ushort4*>(&As[r][kq]) = o;
        }
#pragma unroll
        for (int it = 0; it < 8; ++it) {
            int kq = hf * 4 + it * 8;
            const float* p = w1e + (size_t)(k0 + kq) * I2 + gcol;
            float v0 = p[0], v1 = p[I2], v2 = p[2 * I2], v3 = p[3 * I2];
            ushort4 o;
            o.x = f2bf(v0); o.y = f2bf(v1); o.z = f2bf(v2); o.w = f2bf(v3);
            *reinterpret_cast<ushort4*>(&Bs[jcol][kq]) = o;
        }
        __syncthreads();
#pragma unroll
        for (int kk = 0; kk < 2; ++kk) {
            const int kb = kk * 32 + ((lane >> 4) << 3);
            bf16x8 a0 = *reinterpret_cast<const bf16x8*>(&As[w * 32 + (lane & 15)][kb]);
            bf16x8 a1 = *reinterpret_cast<const bf16x8*>(&As[w * 32 + 16 + (lane & 15)][kb]);
#pragma unroll
            for (int nf = 0; nf < 8; ++nf) {
                bf16x8 b = *reinterpret_cast<const bf16x8*>(&Bs[nf * 16 + (lane & 15)][kb]);
                acc[0][nf] = MFMA_BF16(a0, b, acc[0][nf]);
                acc[1][nf] = MFMA_BF16(a1, b, acc[1][nf]);
            }
        }
        __syncthreads();
    }
    const int rl0 = w * 32 + ((lane >> 4) << 2);
    const int cl  = lane & 15;
#pragma unroll
    for (int mf = 0; mf < 2; ++mf)
#pragma unroll
        for (int nfa = 0; nfa < 4; ++nfa) {
            f32x4 va = acc[mf][nfa];
            f32x4 vb = acc[mf][nfa + 4];
#pragma unroll
            for (int r = 0; r < 4; ++r) {
                float a = va[r], b = vb[r];
                float s = a / (1.f + __expf(-a)) * b;
                int row = rowbase + rl0 + mf * 16 + r;
                int col = nt * 64 + nfa * 16 + cl;
                inter[(size_t)row * INTER + col] = f2bf(s);
            }
        }
}

__global__ __launch_bounds__(256) void k_fc2_fb(
    const unsigned short* __restrict__ inter, const float* __restrict__ W2,
    float* __restrict__ out)
{
    __shared__ unsigned short As[BM][LDK];
    __shared__ unsigned short Bs[128][LDK];
    const int bid = blockIdx.x;
    const int nt  = bid % (HID / 128);
    const int mt  = (bid / (HID / 128)) % (TOK / BM);
    const int e   = bid / ((HID / 128) * (TOK / BM));
    const int t = threadIdx.x, lane = t & 63, w = t >> 6;
    const int m0 = mt * BM;
    const int rowbase = e * TOK + m0;
    f32x4 acc[2][8];
#pragma unroll
    for (int i = 0; i < 2; ++i)
#pragma unroll
        for (int jj = 0; jj < 8; ++jj) acc[i][jj] = f32x4{0.f, 0.f, 0.f, 0.f};
    const int jcol = t & 127;
    const int hf   = t >> 7;
    const int gcol = nt * 128 + jcol;
    const float* w2e = W2 + (size_t)e * INTER * HID;
    for (int k0 = 0; k0 < INTER; k0 += BK) {
#pragma unroll
        for (int it = 0; it < 4; ++it) {
            int lin = it * 256 + t;
            int r   = lin >> 3;
            int kq  = (lin & 7) << 3;
            uint4 v = *reinterpret_cast<const uint4*>(
                inter + (size_t)(rowbase + r) * INTER + k0 + kq);
            *reinterpret_cast<uint4*>(&As[r][kq]) = v;
        }
#pragma unroll
        for (int it = 0; it < 8; ++it) {
            int kq = hf * 4 + it * 8;
            const float* p = w2e + (size_t)(k0 + kq) * HID + gcol;
            float v0 = p[0], v1 = p[HID], v2 = p[2 * HID], v3 = p[3 * HID];
            ushort4 o;
            o.x = f2bf(v0); o.y = f2bf(v1); o.z = f2bf(v2); o.w = f2bf(v3);
            *reinterpret_cast<ushort4*>(&Bs[jcol][kq]) = o;
        }
        __syncthreads();
#pragma unroll
        for (int kk = 0; kk < 2; ++kk) {
            const int kb = kk * 32 + ((lane >> 4) << 3);
            bf16x8 a0 = *reinterpret_cast<const bf16x8*>(&As[w * 32 + (lane & 15)][kb]);
            bf16x8 a1 = *reinterpret_cast<const bf16x8*>(&As[w * 32 + 16 + (lane & 15)][kb]);
#pragma unroll
            for (int nf = 0; nf < 8; ++nf) {
                bf16x8 b = *reinterpret_cast<const bf16x8*>(&Bs[nf * 16 + (lane & 15)][kb]);
                acc[0][nf] = MFMA_BF16(a0, b, acc[0][nf]);
                acc[1][nf] = MFMA_BF16(a1, b, acc[1][nf]);
            }
        }
        __syncthreads();
    }
    const int rl0 = w * 32 + ((lane >> 4) << 2);
    const int cl  = lane & 15;
#pragma unroll
    for (int mf = 0; mf < 2; ++mf)
#pragma unroll
        for (int nf = 0; nf < 8; ++nf) {
            f32x4 v = acc[mf][nf];
#pragma unroll
            for (int r = 0; r < 4; ++r) {
                int row = rowbase + rl0 + mf * 16 + r;
                int col = nt * 128 + nf * 16 + cl;
                out[(size_t)row * HID + col] = v[r];
            }
        }
}

// ---------------- launch ----------------

extern "C" void kernel_launch(void* const* d_in, const int* in_sizes, int n_in,
                              void* d_out, int out_size, void* d_ws, size_t ws_size,
                              hipStream_t stream) {
    const float* X  = (const float*)d_in[0];
    const float* W1 = (const float*)d_in[1];
    const float* W2 = (const float*)d_in[2];
    float* out = (float*)d_out;

    const size_t XB_B  = (size_t)EXPERTS * TOK * HID * 2;
    const size_t W1T_B = (size_t)EXPERTS * I2 * HID * 2;
    const size_t W2T_B = (size_t)EXPERTS * HID * INTER * 2;
    const size_t INT_B = (size_t)EXPERTS * TOK * INTER * 2;
    const size_t need  = XB_B + W1T_B + W2T_B + INT_B;

    if (ws_size >= need) {
        unsigned short* Xb    = (unsigned short*)d_ws;
        unsigned short* w1t   = (unsigned short*)((char*)d_ws + XB_B);
        unsigned short* w2t   = (unsigned short*)((char*)d_ws + XB_B + W1T_B);
        unsigned short* inter = (unsigned short*)((char*)d_ws + XB_B + W1T_B + W2T_B);

        static bool attr_done = false;
        if (!attr_done) {
            hipFuncSetAttribute((const void*)k_fc1_8p,
                hipFuncAttributeMaxDynamicSharedMemorySize, 131072);
            hipFuncSetAttribute((const void*)k_fc2_8p,
                hipFuncAttributeMaxDynamicSharedMemorySize, 131072);
            attr_done = true;
        }

        dim3 b256(256), b512(512);
        k_cvt_x <<<(EXPERTS * TOK * HID) / (256 * 8), b256, 0, stream>>>(X, Xb);
        k_cvt_w1<<<EXPERTS * (I2 / 64) * (HID / 64),   b256, 0, stream>>>(W1, w1t);
        k_cvt_w2<<<EXPERTS * (HID / 64) * (INTER / 64), b256, 0, stream>>>(W2, w2t);
        k_fc1_8p<<<EXPERTS * 4 * (I2 / 256),  b512, 131072, stream>>>(Xb, w1t, inter);
        k_fc2_8p<<<EXPERTS * 4 * (HID / 256), b512, 131072, stream>>>(inter, w2t, out);
    } else {
        unsigned short* inter = (unsigned short*)d_ws;
        dim3 b256(256);
        k_fc1_glu_fb<<<EXPERTS * (TOK / BM) * (INTER / 64), b256, 0, stream>>>(X, W1, inter);
        k_fc2_fb    <<<EXPERTS * (TOK / BM) * (HID / 128),  b256, 0, stream>>>(inter, W2, out);
    }
}

// Round 4
// 1340.927 us; speedup vs baseline: 1.0216x; 1.0216x over previous
//
#include <hip/hip_runtime.h>
#include <hip/hip_bf16.h>

// GroupedMLP: E=8, T=1024, H=2048, I=5632
// Round 4: identical to round 3 EXCEPT block ordering inside each expert is
// mt-innermost (idx = nt*4 + mt), so the 4 co-resident blocks per nt share
// one B-panel (fetched once, 4 concurrent readers) instead of 32 distinct
// panels streaming through L2. This removes the 4x B re-fetch that made the
// counted-vmcnt pipeline memory-infeasible (needed 6.6 TB/s > 6.3 achievable).

#define EXPERTS 8
#define TOK     1024
#define HID     2048
#define INTER   5632
#define I2      (2 * INTER)

typedef __bf16 bf16x8 __attribute__((ext_vector_type(8)));
typedef float  f32x4  __attribute__((ext_vector_type(4)));

__device__ __forceinline__ unsigned short f2bf(float f) {
    union { float f; unsigned u; } v; v.f = f;
    unsigned r = v.u + 0x7FFFu + ((v.u >> 16) & 1u);   // RNE
    return (unsigned short)(r >> 16);
}

__device__ __forceinline__ void gload_lds16(const void* g, void* l) {
    __builtin_amdgcn_global_load_lds(
        (const __attribute__((address_space(1))) void*)g,
        (__attribute__((address_space(3))) void*)l, 16, 0, 0);
}

// swizzled fragment read: tile is [256][64] bf16, element k-slot XORed by row&7
__device__ __forceinline__ bf16x8 ldfrag(const unsigned short* S, int R, int kb) {
    int off = R * 64 + (kb ^ ((R & 7) << 3));
    return *reinterpret_cast<const bf16x8*>(S + off);
}

// ---------------- converts (write swizzled ws layouts) ----------------

// X fp32 -> Xb bf16 [8192][2048], k-slot swizzled by row&7
__global__ __launch_bounds__(256) void k_cvt_x(const float* __restrict__ X,
                                               unsigned short* __restrict__ Xb) {
    size_t base = ((size_t)blockIdx.x * 256 + threadIdx.x) * 8;
    int row = (int)(base >> 11);           // /HID
    int k   = (int)(base & (HID - 1));
    int kp  = k ^ ((row & 7) << 3);
    float4 v0 = *reinterpret_cast<const float4*>(X + base);
    float4 v1 = *reinterpret_cast<const float4*>(X + base + 4);
    uint4 o;
    o.x = (unsigned)f2bf(v0.x) | ((unsigned)f2bf(v0.y) << 16);
    o.y = (unsigned)f2bf(v0.z) | ((unsigned)f2bf(v0.w) << 16);
    o.z = (unsigned)f2bf(v1.x) | ((unsigned)f2bf(v1.y) << 16);
    o.w = (unsigned)f2bf(v1.z) | ((unsigned)f2bf(v1.w) << 16);
    *reinterpret_cast<uint4*>(Xb + (size_t)row * HID + kp) = o;
}

// w1[e][h][2I] fp32 -> w1t[e][pc][h] bf16, pc = 2n + c (GLU interleave), h-slot swizzled
__global__ __launch_bounds__(256) void k_cvt_w1(const float* __restrict__ W1,
                                                unsigned short* __restrict__ W1T) {
    __shared__ unsigned short lds[64][72];
    const int bid = blockIdx.x;
    const int hb = bid % (HID / 64);
    const int pb = (bid / (HID / 64)) % (I2 / 64);
    const int e  = bid / ((HID / 64) * (I2 / 64));
    const int h0 = hb * 64, p0 = pb * 64, n0 = p0 >> 1;
    const float* w1e = W1 + (size_t)e * HID * I2;
    const int t = threadIdx.x;
#pragma unroll
    for (int it = 0; it < 16; ++it) {
        int lin   = it * 256 + t;
        int n_off = lin & 31;
        int c     = (lin >> 5) & 1;
        int h_off = lin >> 6;
        float v = w1e[(size_t)(h0 + h_off) * I2 + c * INTER + n0 + n_off];
        lds[2 * n_off + c][h_off] = f2bf(v);
    }
    __syncthreads();
    unsigned short* o = W1T + (size_t)e * I2 * HID;
#pragma unroll
    for (int it = 0; it < 4; ++it) {
        int lin = it * 256 + t;
        int r   = lin >> 4;
        int co  = (lin & 15) * 4;
        int cop = co ^ ((r & 7) << 3);       // swizzle h-slot by row(pc)&7
        ushort4 v = *reinterpret_cast<ushort4*>(&lds[r][co]);
        *reinterpret_cast<ushort4*>(o + (size_t)(p0 + r) * HID + h0 + cop) = v;
    }
}

// w2[e][i][H] fp32 -> w2t[e][h][i] bf16, i-slot swizzled by h&7
__global__ __launch_bounds__(256) void k_cvt_w2(const float* __restrict__ W2,
                                                unsigned short* __restrict__ W2T) {
    __shared__ unsigned short lds[64][72];
    const int bid = blockIdx.x;
    const int ib = bid % (INTER / 64);
    const int hb = (bid / (INTER / 64)) % (HID / 64);
    const int e  = bid / ((INTER / 64) * (HID / 64));
    const int i0 = ib * 64, h0 = hb * 64;
    const float* w2e = W2 + (size_t)e * INTER * HID;
    const int t = threadIdx.x;
#pragma unroll
    for (int it = 0; it < 16; ++it) {
        int lin   = it * 256 + t;
        int h_off = lin & 63;
        int i_off = lin >> 6;
        float v = w2e[(size_t)(i0 + i_off) * HID + h0 + h_off];
        lds[h_off][i_off] = f2bf(v);
    }
    __syncthreads();
    unsigned short* o = W2T + (size_t)e * HID * INTER;
#pragma unroll
    for (int it = 0; it < 4; ++it) {
        int lin = it * 256 + t;
        int r   = lin >> 4;
        int co  = (lin & 15) * 4;
        int cop = co ^ ((r & 7) << 3);
        ushort4 v = *reinterpret_cast<ushort4*>(&lds[r][co]);
        *reinterpret_cast<ushort4*>(o + (size_t)(h0 + r) * INTER + i0 + cop) = v;
    }
}

// ---------------- 256^2 8-wave GEMM core ----------------
// A [Mrows][ktot], B [Nrows][ktot], both bf16 K-contiguous, pre-swizzled.
// 512 threads = 8 waves (2 row-groups x 4 col-groups), per-wave C = 128x64.
// LDS: 2 buffers x (A 256x64 + B 256x64) = 128 KB (dynamic).

__device__ __forceinline__ void stage_tile(const unsigned short* Ab, const unsigned short* Bb,
                                           int ktot, int k0,
                                           unsigned short* Adst, unsigned short* Bdst,
                                           int t, int w) {
#pragma unroll
    for (int j = 0; j < 4; ++j) {
        int row = j * 64 + (t >> 3);
        int col = (t & 7) * 8;
        gload_lds16(Ab + (size_t)row * ktot + k0 + col, Adst + j * 4096 + w * 512);
        gload_lds16(Bb + (size_t)row * ktot + k0 + col, Bdst + j * 4096 + w * 512);
    }
}

#define MFMA_BF16(a, b, c) __builtin_amdgcn_mfma_f32_16x16x32_bf16(a, b, c, 0, 0, 0)

__device__ __forceinline__ void gemm_core(const unsigned short* Ab, const unsigned short* Bb,
                                          int ktot, int nkt, f32x4 (&acc)[8][4],
                                          unsigned short* lds,
                                          int t, int lane, int w, int wr, int wc) {
    unsigned short* As[2] = { lds,          lds + 32768 };
    unsigned short* Bs[2] = { lds + 16384,  lds + 49152 };

    // prologue: K0 -> buf0, K1 -> buf1; wait K0 (8 of 16 loads), keep K1 in flight
    stage_tile(Ab, Bb, ktot, 0,  As[0], Bs[0], t, w);
    stage_tile(Ab, Bb, ktot, 64, As[1], Bs[1], t, w);
    asm volatile("s_waitcnt vmcnt(8)" ::: "memory");
    __builtin_amdgcn_s_barrier();
    asm volatile("" ::: "memory");

    const int cl = lane & 15;
    const int kb0 = (lane >> 4) << 3;

    for (int kt = 0; kt < nkt; ++kt) {
        const unsigned short* Ac = As[kt & 1];
        const unsigned short* Bc = Bs[kt & 1];
        bf16x8 a[4][2], b[4][2];

        // ---- P1: read A-quad 0 (8) + B pair 0 (4); MFMA q(0,0) ----
#pragma unroll
        for (int i = 0; i < 4; ++i)
#pragma unroll
            for (int k = 0; k < 2; ++k)
                a[i][k] = ldfrag(Ac, wr + i * 16 + cl, k * 32 + kb0);
#pragma unroll
        for (int i = 0; i < 2; ++i)
#pragma unroll
            for (int k = 0; k < 2; ++k)
                b[i][k] = ldfrag(Bc, wc + i * 16 + cl, k * 32 + kb0);
        __builtin_amdgcn_s_barrier();
        __builtin_amdgcn_s_setprio(1);
#pragma unroll
        for (int i = 0; i < 4; ++i)
#pragma unroll
            for (int j = 0; j < 2; ++j)
#pragma unroll
                for (int k = 0; k < 2; ++k)
                    acc[i][j] = MFMA_BF16(a[i][k], b[j][k], acc[i][j]);
        __builtin_amdgcn_s_setprio(0);
        __builtin_amdgcn_s_barrier();

        // ---- P2: read B pair 1 (4); MFMA q(0,1) ----
#pragma unroll
        for (int i = 2; i < 4; ++i)
#pragma unroll
            for (int k = 0; k < 2; ++k)
                b[i][k] = ldfrag(Bc, wc + i * 16 + cl, k * 32 + kb0);
        __builtin_amdgcn_s_barrier();
        __builtin_amdgcn_s_setprio(1);
#pragma unroll
        for (int i = 0; i < 4; ++i)
#pragma unroll
            for (int j = 2; j < 4; ++j)
#pragma unroll
                for (int k = 0; k < 2; ++k)
                    acc[i][j] = MFMA_BF16(a[i][k], b[j][k], acc[i][j]);
        __builtin_amdgcn_s_setprio(0);
        __builtin_amdgcn_s_barrier();

        // ---- P3: read A-quad 1 (8); MFMA q(1,0) ----
#pragma unroll
        for (int i = 0; i < 4; ++i)
#pragma unroll
            for (int k = 0; k < 2; ++k)
                a[i][k] = ldfrag(Ac, wr + 64 + i * 16 + cl, k * 32 + kb0);
        __builtin_amdgcn_s_barrier();
        __builtin_amdgcn_s_setprio(1);
#pragma unroll
        for (int i = 0; i < 4; ++i)
#pragma unroll
            for (int j = 0; j < 2; ++j)
#pragma unroll
                for (int k = 0; k < 2; ++k)
                    acc[4 + i][j] = MFMA_BF16(a[i][k], b[j][k], acc[4 + i][j]);
        __builtin_amdgcn_s_setprio(0);
        __builtin_amdgcn_s_barrier();

        // ---- P4: MFMA q(1,1); end-of-read barrier ----
        __builtin_amdgcn_s_setprio(1);
#pragma unroll
        for (int i = 0; i < 4; ++i)
#pragma unroll
            for (int j = 2; j < 4; ++j)
#pragma unroll
                for (int k = 0; k < 2; ++k)
                    acc[4 + i][j] = MFMA_BF16(a[i][k], b[j][k], acc[4 + i][j]);
        __builtin_amdgcn_s_setprio(0);
        __builtin_amdgcn_s_barrier();           // all waves done reading buf kt&1
        asm volatile("" ::: "memory");

        // ---- stage K(t+2) into the buffer just freed; counted wait ----
        if (kt + 2 < nkt) {
            stage_tile(Ab, Bb, ktot, (kt + 2) * 64, As[kt & 1], Bs[kt & 1], t, w);
            asm volatile("s_waitcnt vmcnt(8)" ::: "memory");   // K(t+1) done, K(t+2) in flight
            __builtin_amdgcn_s_barrier();
            asm volatile("" ::: "memory");
        } else if (kt + 1 < nkt) {
            asm volatile("s_waitcnt vmcnt(0)" ::: "memory");   // last prefetched tile
            __builtin_amdgcn_s_barrier();
            asm volatile("" ::: "memory");
        }
    }
}

// fc1: Xb @ w1t^T -> inter bf16 (GLU fused, swizzled store)
__global__ __launch_bounds__(512, 2) void k_fc1_8p(const unsigned short* __restrict__ Xb,
                                                   const unsigned short* __restrict__ W1T,
                                                   unsigned short* __restrict__ inter) {
    extern __shared__ unsigned short lds[];
    const int hw  = blockIdx.x;                // 1408 blocks = 8 XCDs * 176
    const int e   = hw & 7;                    // expert pinned to XCD (hw%8)
    const int idx = hw >> 3;                   // 0..175, XCD-local launch order
    const int mt  = idx & 3;                   // mt INNERMOST: co-resident blocks
    const int nt  = idx >> 2;                  // share one B-panel (4-way)
    const int t = threadIdx.x, lane = t & 63, w = t >> 6;
    const int wr = (w >> 2) * 128, wc = (w & 3) * 64;
    const int m0 = e * TOK + mt * 256;
    const int n0 = nt * 256;                   // pc-space
    const unsigned short* Ab = Xb  + (size_t)m0 * HID;
    const unsigned short* Bb = W1T + (size_t)e * I2 * HID + (size_t)n0 * HID;

    f32x4 acc[8][4];
#pragma unroll
    for (int i = 0; i < 8; ++i)
#pragma unroll
        for (int j = 0; j < 4; ++j) acc[i][j] = f32x4{0.f, 0.f, 0.f, 0.f};

    gemm_core(Ab, Bb, HID, HID / 64, acc, lds, t, lane, w, wr, wc);

    // epilogue: adjacent pc lanes hold (a,b); even lanes store silu(a)*b
    const int cl = lane & 15;
    const int r0 = (lane >> 4) << 2;
#pragma unroll
    for (int mf = 0; mf < 8; ++mf)
#pragma unroll
        for (int nf = 0; nf < 4; ++nf)
#pragma unroll
            for (int r = 0; r < 4; ++r) {
                float v  = acc[mf][nf][r];
                float pv = __shfl_xor(v, 1);
                if ((lane & 1) == 0) {
                    float s = v / (1.f + __expf(-v)) * pv;
                    int row = m0 + wr + mf * 16 + r0 + r;
                    int pc  = n0 + wc + nf * 16 + cl;
                    int c   = pc >> 1;
                    int c2  = (c & ~63) | ((c & 63) ^ ((row & 7) << 3));  // swizzle
                    inter[(size_t)row * INTER + c2] = f2bf(s);
                }
            }
}

// fc2: inter @ w2t^T -> out fp32
__global__ __launch_bounds__(512, 2) void k_fc2_8p(const unsigned short* __restrict__ A,
                                                   const unsigned short* __restrict__ W2T,
                                                   float* __restrict__ out) {
    extern __shared__ unsigned short lds[];
    const int hw  = blockIdx.x;                // 256 blocks = 8 XCDs * 32
    const int e   = hw & 7;
    const int idx = hw >> 3;                   // 0..31
    const int mt  = idx & 3;                   // mt innermost
    const int nt  = idx >> 2;                  // 0..7
    const int t = threadIdx.x, lane = t & 63, w = t >> 6;
    const int wr = (w >> 2) * 128, wc = (w & 3) * 64;
    const int m0 = e * TOK + mt * 256;
    const int n0 = nt * 256;
    const unsigned short* Ab = A   + (size_t)m0 * INTER;
    const unsigned short* Bb = W2T + (size_t)e * HID * INTER + (size_t)n0 * INTER;

    f32x4 acc[8][4];
#pragma unroll
    for (int i = 0; i < 8; ++i)
#pragma unroll
        for (int j = 0; j < 4; ++j) acc[i][j] = f32x4{0.f, 0.f, 0.f, 0.f};

    gemm_core(Ab, Bb, INTER, INTER / 64, acc, lds, t, lane, w, wr, wc);

    const int cl = lane & 15;
    const int r0 = (lane >> 4) << 2;
#pragma unroll
    for (int mf = 0; mf < 8; ++mf)
#pragma unroll
        for (int nf = 0; nf < 4; ++nf)
#pragma unroll
            for (int r = 0; r < 4; ++r) {
                int row = m0 + wr + mf * 16 + r0 + r;
                int col = n0 + wc + nf * 16 + cl;
                out[(size_t)row * HID + col] = acc[mf][nf][r];
            }
}

// ---------------- fallback (round-1 kernels, need only 92 MB ws) ----------------

#define BM  128
#define BK  64
#define LDK 72

__global__ __launch_bounds__(256) void k_fc1_glu_fb(
    const float* __restrict__ X, const float* __restrict__ W1,
    unsigned short* __restrict__ inter)
{
    __shared__ unsigned short As[BM][LDK];
    __shared__ unsigned short Bs[128][LDK];
    const int bid = blockIdx.x;
    const int nt  = bid % (INTER / 64);
    const int mt  = (bid / (INTER / 64)) % (TOK / BM);
    const int e   = bid / ((INTER / 64) * (TOK / BM));
    const int t = threadIdx.x, lane = t & 63, w = t >> 6;
    const int m0 = mt * BM;
    const int rowbase = e * TOK + m0;
    f32x4 acc[2][8];
#pragma unroll
    for (int i = 0; i < 2; ++i)
#pragma unroll
        for (int jj = 0; jj < 8; ++jj) acc[i][jj] = f32x4{0.f, 0.f, 0.f, 0.f};
    const int jcol = t & 127;
    const int hf   = t >> 7;
    const int gcol = (jcol < 64) ? (nt * 64 + jcol) : (INTER + nt * 64 + (jcol - 64));
    const float* w1e = W1 + (size_t)e * HID * I2;
    for (int k0 = 0; k0 < HID; k0 += BK) {
#pragma unroll
        for (int it = 0; it < 8; ++it) {
            int lin = it * 256 + t;
            int r   = lin >> 4;
            int kq  = (lin & 15) << 2;
            const float4 v = *reinterpret_cast<const float4*>(
                X + (size_t)(rowbase + r) * HID + k0 + kq);
            ushort4 o;
            o.x = f2bf(v.x); o.y = f2bf(v.y); o.z = f2bf(v.z); o.w = f2bf(v.w);
            *reinterpret_cast<ushort4*>(&As[r][kq]) = o;
        }
#pragma unroll
        for (int it = 0; it < 8; ++it) {
            int kq = hf * 4 + it * 8;
            const float* p = w1e + (size_t)(k0 + kq) * I2 + gcol;
            float v0 = p[0], v1 = p[I2], v2 = p[2 * I2], v3 = p[3 * I2];
            ushort4 o;
            o.x = f2bf(v0); o.y = f2bf(v1); o.z = f2bf(v2); o.w = f2bf(v3);
            *reinterpret_cast<ushort4*>(&Bs[jcol][kq]) = o;
        }
        __syncthreads();
#pragma unroll
        for (int kk = 0; kk < 2; ++kk) {
            const int kb = kk * 32 + ((lane >> 4) << 3);
            bf16x8 a0 = *reinterpret_cast<const bf16x8*>(&As[w * 32 + (lane & 15)][kb]);
            bf16x8 a1 = *reinterpret_cast<const bf16x8*>(&As[w * 32 + 16 + (lane & 15)][kb]);
#pragma unroll
            for (int nf = 0; nf < 8; ++nf) {
                bf16x8 b = *reinterpret_cast<const bf16x8*>(&Bs[nf * 16 + (lane & 15)][kb]);
                acc[0][nf] = MFMA_BF16(a0, b, acc[0][nf]);
                acc[1][nf] = MFMA_BF16(a1, b, acc[1][nf]);
            }
        }
        __syncthreads();
    }
    const int rl0 = w * 32 + ((lane >> 4) << 2);
    const int cl  = lane & 15;
#pragma unroll
    for (int mf = 0; mf < 2; ++mf)
#pragma unroll
        for (int nfa = 0; nfa < 4; ++nfa) {
            f32x4 va = acc[mf][nfa];
            f32x4 vb = acc[mf][nfa + 4];
#pragma unroll
            for (int r = 0; r < 4; ++r) {
                float a = va[r], b = vb[r];
                float s = a / (1.f + __expf(-a)) * b;
                int row = rowbase + rl0 + mf * 16 + r;
                int col = nt * 64 + nfa * 16 + cl;
                inter[(size_t)row * INTER + col] = f2bf(s);
            }
        }
}

__global__ __launch_bounds__(256) void k_fc2_fb(
    const unsigned short* __restrict__ inter, const float* __restrict__ W2,
    float* __restrict__ out)
{
    __shared__ unsigned short As[BM][LDK];
    __shared__ unsigned short Bs[128][LDK];
    const int bid = blockIdx.x;
    const int nt  = bid % (HID / 128);
    const int mt  = (bid / (HID / 128)) % (TOK / BM);
    const int e   = bid / ((HID / 128) * (TOK / BM));
    const int t = threadIdx.x, lane = t & 63, w = t >> 6;
    const int m0 = mt * BM;
    const int rowbase = e * TOK + m0;
    f32x4 acc[2][8];
#pragma unroll
    for (int i = 0; i < 2; ++i)
#pragma unroll
        for (int jj = 0; jj < 8; ++jj) acc[i][jj] = f32x4{0.f, 0.f, 0.f, 0.f};
    const int jcol = t & 127;
    const int hf   = t >> 7;
    const int gcol = nt * 128 + jcol;
    const float* w2e = W2 + (size_t)e * INTER * HID;
    for (int k0 = 0; k0 < INTER; k0 += BK) {
#pragma unroll
        for (int it = 0; it < 4; ++it) {
            int lin = it * 256 + t;
            int r   = lin >> 3;
            int kq  = (lin & 7) << 3;
            uint4 v = *reinterpret_cast<const uint4*>(
                inter + (size_t)(rowbase + r) * INTER + k0 + kq);
            *reinterpret_cast<uint4*>(&As[r][kq]) = v;
        }
#pragma unroll
        for (int it = 0; it < 8; ++it) {
            int kq = hf * 4 + it * 8;
            const float* p = w2e + (size_t)(k0 + kq) * HID + gcol;
            float v0 = p[0], v1 = p[HID], v2 = p[2 * HID], v3 = p[3 * HID];
            ushort4 o;
            o.x = f2bf(v0); o.y = f2bf(v1); o.z = f2bf(v2); o.w = f2bf(v3);
            *reinterpret_cast<ushort4*>(&Bs[jcol][kq]) = o;
        }
        __syncthreads();
#pragma unroll
        for (int kk = 0; kk < 2; ++kk) {
            const int kb = kk * 32 + ((lane >> 4) << 3);
            bf16x8 a0 = *reinterpret_cast<const bf16x8*>(&As[w * 32 + (lane & 15)][kb]);
            bf16x8 a1 = *reinterpret_cast<const bf16x8*>(&As[w * 32 + 16 + (lane & 15)][kb]);
#pragma unroll
            for (int nf = 0; nf < 8; ++nf) {
                bf16x8 b = *reinterpret_cast<const bf16x8*>(&Bs[nf * 16 + (lane & 15)][kb]);
                acc[0][nf] = MFMA_BF16(a0, b, acc[0][nf]);
                acc[1][nf] = MFMA_BF16(a1, b, acc[1][nf]);
            }
        }
        __syncthreads();
    }
    const int rl0 = w * 32 + ((lane >> 4) << 2);
    const int cl  = lane & 15;
#pragma unroll
    for (int mf = 0; mf < 2; ++mf)
#pragma unroll
        for (int nf = 0; nf < 8; ++nf) {
            f32x4 v = acc[mf][nf];
#pragma unroll
            for (int r = 0; r < 4; ++r) {
                int row = rowbase + rl0 + mf * 16 + r;
                int col = nt * 128 + nf * 16 + cl;
                out[(size_t)row * HID + col] = v[r];
            }
        }
}

// ---------------- launch ----------------

extern "C" void kernel_launch(void* const* d_in, const int* in_sizes, int n_in,
                              void* d_out, int out_size, void* d_ws, size_t ws_size,
                              hipStream_t stream) {
    const float* X  = (const float*)d_in[0];
    const float* W1 = (const float*)d_in[1];
    const float* W2 = (const float*)d_in[2];
    float* out = (float*)d_out;

    const size_t XB_B  = (size_t)EXPERTS * TOK * HID * 2;
    const size_t W1T_B = (size_t)EXPERTS * I2 * HID * 2;
    const size_t W2T_B = (size_t)EXPERTS * HID * INTER * 2;
    const size_t INT_B = (size_t)EXPERTS * TOK * INTER * 2;
    const size_t need  = XB_B + W1T_B + W2T_B + INT_B;

    if (ws_size >= need) {
        unsigned short* Xb    = (unsigned short*)d_ws;
        unsigned short* w1t   = (unsigned short*)((char*)d_ws + XB_B);
        unsigned short* w2t   = (unsigned short*)((char*)d_ws + XB_B + W1T_B);
        unsigned short* inter = (unsigned short*)((char*)d_ws + XB_B + W1T_B + W2T_B);

        static bool attr_done = false;
        if (!attr_done) {
            hipFuncSetAttribute((const void*)k_fc1_8p,
                hipFuncAttributeMaxDynamicSharedMemorySize, 131072);
            hipFuncSetAttribute((const void*)k_fc2_8p,
                hipFuncAttributeMaxDynamicSharedMemorySize, 131072);
            attr_done = true;
        }

        dim3 b256(256), b512(512);
        k_cvt_x <<<(EXPERTS * TOK * HID) / (256 * 8), b256, 0, stream>>>(X, Xb);
        k_cvt_w1<<<EXPERTS * (I2 / 64) * (HID / 64),   b256, 0, stream>>>(W1, w1t);
        k_cvt_w2<<<EXPERTS * (HID / 64) * (INTER / 64), b256, 0, stream>>>(W2, w2t);
        k_fc1_8p<<<EXPERTS * 4 * (I2 / 256),  b512, 131072, stream>>>(Xb, w1t, inter);
        k_fc2_8p<<<EXPERTS * 4 * (HID / 256), b512, 131072, stream>>>(inter, w2t, out);
    } else {
        unsigned short* inter = (unsigned short*)d_ws;
        dim3 b256(256);
        k_fc1_glu_fb<<<EXPERTS * (TOK / BM) * (INTER / 64), b256, 0, stream>>>(X, W1, inter);
        k_fc2_fb    <<<EXPERTS * (TOK / BM) * (HID / 128),  b256, 0, stream>>>(inter, W2, out);
    }
}